// Round 6
// baseline (350.564 us; speedup 1.0000x reference)
//
#include <hip/hip_runtime.h>
#include <hip/hip_bf16.h>
#include <hip/hip_fp16.h>

#define N_NODES 50000
#define N_EDGES 640000
#define E_TOT   690000   // edges + self-loops
#define CH      128
#define SCAN_NB ((N_NODES + 255) / 256)   // 196 scan blocks

typedef __attribute__((ext_vector_type(8))) short short8;
typedef __attribute__((ext_vector_type(4))) float float4v;

static __device__ __forceinline__ float bf2f(unsigned short u) {
  return __uint_as_float(((unsigned)u) << 16);
}
static __device__ __forceinline__ unsigned short f2bf(float f) {
  unsigned u = __float_as_uint(f);
  return (unsigned short)((u + 0x7fffu + ((u >> 16) & 1u)) >> 16);
}

// ---- runtime dtype detection (parallel, 1 block) ------------------------
__global__ void k_detect(const unsigned short* __restrict__ x16,
                         const unsigned int* __restrict__ eiw,
                         int* __restrict__ flags)
{
  __shared__ int sf32, si64;
  int t = threadIdx.x;
  if (t == 0) { sf32 = 0; si64 = 1; }
  __syncthreads();
  int bad = 0;
  for (int i = t; i < 4096; i += 256) {
    float v = bf2f(x16[i]);
    if (!(v == v) || fabsf(v) > 100.f) bad = 1;
  }
  if (bad) atomicOr(&sf32, 1);
  if (t < 128 && eiw[2 * t + 1] != 0u) atomicAnd(&si64, 0);
  __syncthreads();
  if (t == 0) { flags[0] = sf32; flags[1] = si64; }
}

static __device__ __forceinline__ void load_edge(const int* __restrict__ ei,
                                                 int e, int i64, int& s, int& d)
{
  if (e >= N_EDGES) { s = d = e - N_EDGES; return; }
  if (i64) { s = ei[2 * (size_t)e]; d = ei[2 * ((size_t)N_EDGES + e)]; }
  else     { s = ei[e];             d = ei[N_EDGES + e]; }
}

static __device__ __forceinline__ short8 load_bf8(const void* __restrict__ X,
                                                  size_t off, int f32)
{
  if (!f32) return *(const short8*)((const unsigned short*)X + off);
  const float4* p = (const float4*)((const float*)X + off);
  float4 u = p[0], v = p[1];
  short8 r;
  r[0] = (short)f2bf(u.x); r[1] = (short)f2bf(u.y);
  r[2] = (short)f2bf(u.z); r[3] = (short)f2bf(u.w);
  r[4] = (short)f2bf(v.x); r[5] = (short)f2bf(v.y);
  r[6] = (short)f2bf(v.z); r[7] = (short)f2bf(v.w);
  return r;
}

// ---- CSR build: count -> 3-kernel scan -> fill --------------------------
__global__ __launch_bounds__(256) void k_count(
    const int* __restrict__ ei, int* __restrict__ deg,
    const int* __restrict__ flags)
{
  int e = blockIdx.x * 256 + threadIdx.x;
  if (e >= E_TOT) return;
  int s, d;
  load_edge(ei, e, flags[1], s, d);
  atomicAdd(&deg[d], 1);
}

__global__ __launch_bounds__(256) void k_scan1(
    const int* __restrict__ deg, int* __restrict__ row_ptr,
    int* __restrict__ bsum)
{
  __shared__ int sh[256];
  int t = threadIdx.x, g = blockIdx.x * 256 + t;
  int v = (g < N_NODES) ? deg[g] : 0;
  sh[t] = v;
  __syncthreads();
  for (int off = 1; off < 256; off <<= 1) {
    int u = (t >= off) ? sh[t - off] : 0;
    __syncthreads();
    sh[t] += u;
    __syncthreads();
  }
  if (g < N_NODES) row_ptr[g] = sh[t] - v;
  if (t == 255) bsum[blockIdx.x] = sh[255];
}

__global__ __launch_bounds__(256) void k_scan2(int* __restrict__ bsum)
{
  __shared__ int sh[256];
  int t = threadIdx.x;
  int v = (t < SCAN_NB) ? bsum[t] : 0;
  sh[t] = v;
  __syncthreads();
  for (int off = 1; off < 256; off <<= 1) {
    int u = (t >= off) ? sh[t - off] : 0;
    __syncthreads();
    sh[t] += u;
    __syncthreads();
  }
  if (t < SCAN_NB) bsum[t] = sh[t] - v;
}

__global__ __launch_bounds__(256) void k_scan3(
    int* __restrict__ row_ptr, const int* __restrict__ bsum,
    int* __restrict__ cursor)
{
  int g = blockIdx.x * 256 + threadIdx.x;
  if (g >= N_NODES) return;
  int v = row_ptr[g] + bsum[blockIdx.x];
  row_ptr[g] = v;
  cursor[g] = v;
}

__global__ __launch_bounds__(256) void k_fill(
    const int* __restrict__ ei, int* __restrict__ cursor,
    int* __restrict__ csr_src, const int* __restrict__ flags)
{
  int e = blockIdx.x * 256 + threadIdx.x;
  if (e >= E_TOT) return;
  int s, d;
  load_edge(ei, e, flags[1], s, d);
  int pos = atomicAdd(&cursor[d], 1);
  csr_src[pos] = s;
}

// ---- H (fp16) = X @ W, bf16 MFMA 16x16x32, fused alpha epilogue ---------
// Epilogue routes accumulators through a per-wave LDS tile so global H
// stores are 16B/lane covering full 256B rows (fixes 2.9x write amplification
// from scattered 2-byte __half stores seen in r5: WRITE 39.3MB vs 13.6 ideal).
__global__ __launch_bounds__(256) void k_gemm(
    const void* __restrict__ X, const void* __restrict__ W,
    const void* __restrict__ a_src, const void* __restrict__ a_dst,
    unsigned short* __restrict__ H, float* __restrict__ AS, float* __restrict__ AD,
    int nrows, const int* __restrict__ flags, int xmode)
{
  int f32 = flags[0];
  int xf32 = xmode ? 0 : f32;
  __shared__ short Wt[CH][CH + 8];
  __shared__ float ss[CH], sd[CH];
  __shared__ unsigned short T[4][16][132];   // per-wave transpose tile (+4 pad)
  int tid = threadIdx.x;
  if (tid < CH) {
    ss[tid] = f32 ? ((const float*)a_src)[tid] : bf2f(((const unsigned short*)a_src)[tid]);
    sd[tid] = f32 ? ((const float*)a_dst)[tid] : bf2f(((const unsigned short*)a_dst)[tid]);
  }
#pragma unroll
  for (int i = 0; i < (CH * CH) / 256; i++) {
    int idx = tid + i * 256;
    int k = idx >> 7, c = idx & 127;
    Wt[c][k] = f32 ? (short)f2bf(((const float*)W)[idx])
                   : (short)((const unsigned short*)W)[idx];
  }
  __syncthreads();
  int wave = tid >> 6, lane = tid & 63;
  int rt = blockIdx.x * 4 + wave;
  if (rt * 16 >= nrows) return;
  int R0 = rt * 16;
  int m = lane & 15, quad = lane >> 4;
  size_t abase = (size_t)(R0 + m) * CH + quad * 8;
  float4v acc[8];
#pragma unroll
  for (int t = 0; t < 8; t++) acc[t] = (float4v){0.f, 0.f, 0.f, 0.f};
#pragma unroll
  for (int kb = 0; kb < 4; kb++) {
    short8 a = load_bf8(X, abase + kb * 32, xf32);
#pragma unroll
    for (int ct = 0; ct < 8; ct++) {
      short8 b = *(const short8*)&Wt[ct * 16 + m][kb * 32 + quad * 8];
      acc[ct] = __builtin_amdgcn_mfma_f32_16x16x32_bf16(a, b, acc[ct], 0, 0, 0);
    }
  }
  // ---- H store via per-wave LDS transpose (wave-private: no barrier;
  // DS ops from one wave execute in order) ----
#pragma unroll
  for (int ct = 0; ct < 8; ct++) {
    int col = ct * 16 + m;
#pragma unroll
    for (int r = 0; r < 4; r++)
      T[wave][quad * 4 + r][col] = __half_as_ushort(__float2half(acc[ct][r]));
  }
  __builtin_amdgcn_wave_barrier();   // keep compiler from reordering ds ops
#pragma unroll
  for (int i = 0; i < 4; i++) {
    int row = i * 4 + quad;
    short8 hv = *(const short8*)&T[wave][row][m * 8];
    *(short8*)(H + (size_t)(R0 + row) * CH + m * 8) = hv;  // 4x256B full rows
  }
  // ---- fused alpha: per-lane partials over this lane's 8 columns ----
  float ssv[8], sdv[8];
#pragma unroll
  for (int ct = 0; ct < 8; ct++) { ssv[ct] = ss[ct * 16 + m]; sdv[ct] = sd[ct * 16 + m]; }
  float ps[4][4], pd[4][4];   // [head][r]
#pragma unroll
  for (int h = 0; h < 4; h++) {
    int c0 = 2 * h, c1 = 2 * h + 1;
#pragma unroll
    for (int r = 0; r < 4; r++) {
      ps[h][r] = acc[c0][r] * ssv[c0] + acc[c1][r] * ssv[c1];
      pd[h][r] = acc[c0][r] * sdv[c0] + acc[c1][r] * sdv[c1];
    }
  }
#pragma unroll
  for (int mask = 1; mask < 16; mask <<= 1) {
#pragma unroll
    for (int h = 0; h < 4; h++)
#pragma unroll
      for (int r = 0; r < 4; r++) {
        ps[h][r] += __shfl_xor(ps[h][r], mask);
        pd[h][r] += __shfl_xor(pd[h][r], mask);
      }
  }
  int rbase = R0 + quad * 4;
  int wh = m >> 2, wr = m & 3;     // lane m writes head wh, row-offset wr
  size_t o = (size_t)(rbase + wr) * 4 + wh;
  AS[o] = ps[wh][wr];
  AD[o] = pd[wh][wr];
}

// ---- fused gather-aggregate + softmax + epilogue, 4-wide unrolled -------
__global__ __launch_bounds__(256) void k_agg(
    const int* __restrict__ row_ptr, const int* __restrict__ deg,
    const int* __restrict__ csr_src,
    const __half* __restrict__ H,
    const float* __restrict__ AS, const float* __restrict__ AD,
    const void* __restrict__ b, void* __restrict__ Y,
    const int* __restrict__ flags, int layer)
{
  int tid = threadIdx.x;
  int node = blockIdx.x * 4 + (tid >> 6);
  if (node >= N_NODES) return;
  int lane = tid & 63;
  int h = lane >> 4;
  int c0 = 2 * lane;
  float adh = AD[(size_t)node * 4 + h];
  int start = row_ptr[node];
  int dg = deg[node];
  const __half2* __restrict__ H2 = (const __half2*)H;
  float accx = 0.f, accy = 0.f, den = 0.f;
  int j = 0;
  for (; j + 4 <= dg; j += 4) {
    int s0 = csr_src[start + j];
    int s1 = csr_src[start + j + 1];
    int s2 = csr_src[start + j + 2];
    int s3 = csr_src[start + j + 3];
    float e0 = AS[(size_t)s0 * 4 + h] + adh;
    float e1 = AS[(size_t)s1 * 4 + h] + adh;
    float e2 = AS[(size_t)s2 * 4 + h] + adh;
    float e3 = AS[(size_t)s3 * 4 + h] + adh;
    float2 v0 = __half22float2(H2[(size_t)s0 * 64 + lane]);
    float2 v1 = __half22float2(H2[(size_t)s1 * 64 + lane]);
    float2 v2 = __half22float2(H2[(size_t)s2 * 64 + lane]);
    float2 v3 = __half22float2(H2[(size_t)s3 * 64 + lane]);
    e0 = e0 > 0.f ? e0 : 0.2f * e0;
    e1 = e1 > 0.f ? e1 : 0.2f * e1;
    e2 = e2 > 0.f ? e2 : 0.2f * e2;
    e3 = e3 > 0.f ? e3 : 0.2f * e3;
    float x0 = __expf(e0), x1 = __expf(e1), x2 = __expf(e2), x3 = __expf(e3);
    accx += x0 * v0.x + x1 * v1.x + x2 * v2.x + x3 * v3.x;
    accy += x0 * v0.y + x1 * v1.y + x2 * v2.y + x3 * v3.y;
    den  += x0 + x1 + x2 + x3;
  }
  for (; j < dg; j++) {
    int s = csr_src[start + j];
    float e = AS[(size_t)s * 4 + h] + adh;
    float2 v = __half22float2(H2[(size_t)s * 64 + lane]);
    e = e > 0.f ? e : 0.2f * e;
    float ex = __expf(e);
    accx += ex * v.x;
    accy += ex * v.y;
    den  += ex;
  }
  float inv = 1.f / (den + 1e-16f);
  int f32 = flags[0];
  float b0 = f32 ? ((const float*)b)[c0]     : bf2f(((const unsigned short*)b)[c0]);
  float b1 = f32 ? ((const float*)b)[c0 + 1] : bf2f(((const unsigned short*)b)[c0 + 1]);
  float r0 = accx * inv + b0;
  float r1 = accy * inv + b1;
  size_t o = (size_t)node * CH + c0;
  if (layer == 1) {                 // relu + bf16 -> X2
    r0 = r0 > 0.f ? r0 : 0.f;
    r1 = r1 > 0.f ? r1 : 0.f;
    ushort2 w; w.x = f2bf(r0); w.y = f2bf(r1);
    *(ushort2*)((unsigned short*)Y + o) = w;
  } else if (f32) {
    float2 w; w.x = r0; w.y = r1;
    *(float2*)((float*)Y + o) = w;
  } else {
    ushort2 w; w.x = f2bf(r0); w.y = f2bf(r1);
    *(ushort2*)((unsigned short*)Y + o) = w;
  }
}

extern "C" void kernel_launch(void* const* d_in, const int* in_sizes, int n_in,
                              void* d_out, int out_size, void* d_ws, size_t ws_size,
                              hipStream_t stream)
{
  const void* x   = d_in[0];
  const int*  ei  = (const int*)d_in[1];
  const void* W1  = d_in[2];
  const void* as1 = d_in[3];
  const void* ad1 = d_in[4];
  const void* b1  = d_in[5];
  const void* W2  = d_in[6];
  const void* as2 = d_in[7];
  const void* ad2 = d_in[8];
  const void* b2  = d_in[9];

  char* ws = (char*)d_ws;
  unsigned short* H  = (unsigned short*)(ws);            // 12,800,000 B (fp16)
  float*  AS         = (float*)(ws + 12800000);          //    800,000 B
  float*  AD         = (float*)(ws + 13600000);          //    800,000 B
  unsigned short* X2 = (unsigned short*)(ws + 14400000); // 12,800,000 B
  int*    deg        = (int*)(ws + 27200000);            //    200,000 B
  int*    row_ptr    = (int*)(ws + 27400064);            //    200,064 B
  int*    cursor     = (int*)(ws + 27600128);            //    200,000 B
  int*    csr_src    = (int*)(ws + 27800128);            //  2,760,000 B
  int*    flags      = (int*)(ws + 30560128);            //         64 B
  int*    bsum       = (int*)(ws + 30560256);            //       1024 B

  const int gemm_blocks  = 3125 / 4 + 1;
  const int edge_blocks  = (E_TOT + 255) / 256;
  const int agg_blocks   = (N_NODES + 3) / 4;            // 1 wave per node

  k_detect<<<1, 256, 0, stream>>>((const unsigned short*)x,
                                  (const unsigned int*)ei, flags);

  // ---- CSR build (shared by both layers) ----
  hipMemsetAsync(deg, 0, (size_t)N_NODES * sizeof(int), stream);
  k_count<<<edge_blocks, 256, 0, stream>>>(ei, deg, flags);
  k_scan1<<<SCAN_NB, 256, 0, stream>>>(deg, row_ptr, bsum);
  k_scan2<<<1, 256, 0, stream>>>(bsum);
  k_scan3<<<SCAN_NB, 256, 0, stream>>>(row_ptr, bsum, cursor);
  k_fill <<<edge_blocks, 256, 0, stream>>>(ei, cursor, csr_src, flags);

  // ---- layer 1 ----
  k_gemm<<<gemm_blocks, 256, 0, stream>>>(x, W1, as1, ad1, H, AS, AD,
                                          N_NODES, flags, 0);
  k_agg <<<agg_blocks,  256, 0, stream>>>(row_ptr, deg, csr_src,
                                          (const __half*)H, AS, AD,
                                          b1, X2, flags, 1);

  // ---- layer 2 ----
  k_gemm<<<gemm_blocks, 256, 0, stream>>>(X2, W2, as2, ad2, H, AS, AD,
                                          N_NODES, flags, 1);
  k_agg <<<agg_blocks,  256, 0, stream>>>(row_ptr, deg, csr_src,
                                          (const __half*)H, AS, AD,
                                          b2, d_out, flags, 2);
}

// Round 7
// 310.577 us; speedup vs baseline: 1.1288x; 1.1288x over previous
//
#include <hip/hip_runtime.h>
#include <hip/hip_bf16.h>
#include <hip/hip_fp16.h>

#define N_NODES 50000
#define N_EDGES 640000
#define E_TOT   690000   // edges + self-loops
#define CH      128
#define SCAN_NB ((N_NODES + 255) / 256)   // 196 scan blocks

typedef __attribute__((ext_vector_type(8))) short short8;
typedef __attribute__((ext_vector_type(4))) float float4v;

static __device__ __forceinline__ float bf2f(unsigned short u) {
  return __uint_as_float(((unsigned)u) << 16);
}
static __device__ __forceinline__ unsigned short f2bf(float f) {
  unsigned u = __float_as_uint(f);
  return (unsigned short)((u + 0x7fffu + ((u >> 16) & 1u)) >> 16);
}

// ---- runtime dtype detection (parallel, 1 block) ------------------------
__global__ void k_detect(const unsigned short* __restrict__ x16,
                         const unsigned int* __restrict__ eiw,
                         int* __restrict__ flags)
{
  __shared__ int sf32, si64;
  int t = threadIdx.x;
  if (t == 0) { sf32 = 0; si64 = 1; }
  __syncthreads();
  int bad = 0;
  for (int i = t; i < 4096; i += 256) {
    float v = bf2f(x16[i]);
    if (!(v == v) || fabsf(v) > 100.f) bad = 1;
  }
  if (bad) atomicOr(&sf32, 1);
  if (t < 128 && eiw[2 * t + 1] != 0u) atomicAnd(&si64, 0);
  __syncthreads();
  if (t == 0) { flags[0] = sf32; flags[1] = si64; }
}

static __device__ __forceinline__ void load_edge(const int* __restrict__ ei,
                                                 int e, int i64, int& s, int& d)
{
  if (e >= N_EDGES) { s = d = e - N_EDGES; return; }
  if (i64) { s = ei[2 * (size_t)e]; d = ei[2 * ((size_t)N_EDGES + e)]; }
  else     { s = ei[e];             d = ei[N_EDGES + e]; }
}

static __device__ __forceinline__ short8 load_bf8(const void* __restrict__ X,
                                                  size_t off, int f32)
{
  if (!f32) return *(const short8*)((const unsigned short*)X + off);
  const float4* p = (const float4*)((const float*)X + off);
  float4 u = p[0], v = p[1];
  short8 r;
  r[0] = (short)f2bf(u.x); r[1] = (short)f2bf(u.y);
  r[2] = (short)f2bf(u.z); r[3] = (short)f2bf(u.w);
  r[4] = (short)f2bf(v.x); r[5] = (short)f2bf(v.y);
  r[6] = (short)f2bf(v.z); r[7] = (short)f2bf(v.w);
  return r;
}

// ---- CSR build: count -> 3-kernel scan -> fill --------------------------
__global__ __launch_bounds__(256) void k_count(
    const int* __restrict__ ei, int* __restrict__ deg,
    const int* __restrict__ flags)
{
  int e = blockIdx.x * 256 + threadIdx.x;
  if (e >= E_TOT) return;
  int s, d;
  load_edge(ei, e, flags[1], s, d);
  atomicAdd(&deg[d], 1);
}

__global__ __launch_bounds__(256) void k_scan1(
    const int* __restrict__ deg, int* __restrict__ row_ptr,
    int* __restrict__ bsum)
{
  __shared__ int sh[256];
  int t = threadIdx.x, g = blockIdx.x * 256 + t;
  int v = (g < N_NODES) ? deg[g] : 0;
  sh[t] = v;
  __syncthreads();
  for (int off = 1; off < 256; off <<= 1) {
    int u = (t >= off) ? sh[t - off] : 0;
    __syncthreads();
    sh[t] += u;
    __syncthreads();
  }
  if (g < N_NODES) row_ptr[g] = sh[t] - v;
  if (t == 255) bsum[blockIdx.x] = sh[255];
}

__global__ __launch_bounds__(256) void k_scan2(int* __restrict__ bsum)
{
  __shared__ int sh[256];
  int t = threadIdx.x;
  int v = (t < SCAN_NB) ? bsum[t] : 0;
  sh[t] = v;
  __syncthreads();
  for (int off = 1; off < 256; off <<= 1) {
    int u = (t >= off) ? sh[t - off] : 0;
    __syncthreads();
    sh[t] += u;
    __syncthreads();
  }
  if (t < SCAN_NB) bsum[t] = sh[t] - v;
}

__global__ __launch_bounds__(256) void k_scan3(
    int* __restrict__ row_ptr, const int* __restrict__ bsum,
    int* __restrict__ cursor)
{
  int g = blockIdx.x * 256 + threadIdx.x;
  if (g >= N_NODES) return;
  int v = row_ptr[g] + bsum[blockIdx.x];
  row_ptr[g] = v;
  cursor[g] = v;
}

__global__ __launch_bounds__(256) void k_fill(
    const int* __restrict__ ei, int* __restrict__ cursor,
    int* __restrict__ csr_src, const int* __restrict__ flags)
{
  int e = blockIdx.x * 256 + threadIdx.x;
  if (e >= E_TOT) return;
  int s, d;
  load_edge(ei, e, flags[1], s, d);
  int pos = atomicAdd(&cursor[d], 1);
  csr_src[pos] = s;
}

// ---- H (fp16) = X @ W, bf16 MFMA 16x16x32, fused alpha epilogue ---------
// r6 lesson: WRITE_SIZE 40MB == 14.4MB ideal + 3125*64 threads * 128B scratch
// spill (ps/pd arrays). Fix: __launch_bounds__(256,2) lifts the VGPR cap to
// 256 (no spill) and the alpha reduction is restructured per-head so peak
// live state is acc(32)+8 floats. H stores are direct 2B stores — L2 merges
// them into full lines (r5/r6 showed no store-pattern amplification).
__global__ __launch_bounds__(256, 2) void k_gemm(
    const void* __restrict__ X, const void* __restrict__ W,
    const void* __restrict__ a_src, const void* __restrict__ a_dst,
    unsigned short* __restrict__ H, float* __restrict__ AS, float* __restrict__ AD,
    int nrows, const int* __restrict__ flags, int xmode)
{
  int f32 = flags[0];
  int xf32 = xmode ? 0 : f32;
  __shared__ short Wt[CH][CH + 8];
  __shared__ float ss[CH], sd[CH];
  int tid = threadIdx.x;
  if (tid < CH) {
    ss[tid] = f32 ? ((const float*)a_src)[tid] : bf2f(((const unsigned short*)a_src)[tid]);
    sd[tid] = f32 ? ((const float*)a_dst)[tid] : bf2f(((const unsigned short*)a_dst)[tid]);
  }
#pragma unroll
  for (int i = 0; i < (CH * CH) / 256; i++) {
    int idx = tid + i * 256;
    int k = idx >> 7, c = idx & 127;
    Wt[c][k] = f32 ? (short)f2bf(((const float*)W)[idx])
                   : (short)((const unsigned short*)W)[idx];
  }
  __syncthreads();
  int wave = tid >> 6, lane = tid & 63;
  int rt = blockIdx.x * 4 + wave;
  if (rt * 16 >= nrows) return;
  int R0 = rt * 16;
  int m = lane & 15, quad = lane >> 4;
  size_t abase = (size_t)(R0 + m) * CH + quad * 8;
  float4v acc[8];
#pragma unroll
  for (int t = 0; t < 8; t++) acc[t] = (float4v){0.f, 0.f, 0.f, 0.f};
#pragma unroll
  for (int kb = 0; kb < 4; kb++) {
    short8 a = load_bf8(X, abase + kb * 32, xf32);
#pragma unroll
    for (int ct = 0; ct < 8; ct++) {
      short8 b = *(const short8*)&Wt[ct * 16 + m][kb * 32 + quad * 8];
      acc[ct] = __builtin_amdgcn_mfma_f32_16x16x32_bf16(a, b, acc[ct], 0, 0, 0);
    }
  }
  // ---- H store: direct 2B stores (C/D layout col=ct*16+m, row=quad*4+r) --
  int rbase = R0 + quad * 4;
#pragma unroll
  for (int ct = 0; ct < 8; ct++) {
    int col = ct * 16 + m;
#pragma unroll
    for (int r = 0; r < 4; r++)
      H[(size_t)(rbase + r) * CH + col] = __half_as_ushort(__float2half(acc[ct][r]));
  }
  // ---- fused alpha, per-head to keep live state small --------------------
  int wh = m >> 2, wr = m & 3;     // lane m writes head wh, row-offset wr
  float vS = 0.f, vD = 0.f;
#pragma unroll
  for (int h = 0; h < 4; h++) {
    int ca = 2 * h, cb = 2 * h + 1;
    float sa = ss[ca * 16 + m], sb = ss[cb * 16 + m];
    float da = sd[ca * 16 + m], db = sd[cb * 16 + m];
    float ps0 = acc[ca][0] * sa + acc[cb][0] * sb;
    float ps1 = acc[ca][1] * sa + acc[cb][1] * sb;
    float ps2 = acc[ca][2] * sa + acc[cb][2] * sb;
    float ps3 = acc[ca][3] * sa + acc[cb][3] * sb;
    float pd0 = acc[ca][0] * da + acc[cb][0] * db;
    float pd1 = acc[ca][1] * da + acc[cb][1] * db;
    float pd2 = acc[ca][2] * da + acc[cb][2] * db;
    float pd3 = acc[ca][3] * da + acc[cb][3] * db;
#pragma unroll
    for (int mask = 1; mask < 16; mask <<= 1) {
      ps0 += __shfl_xor(ps0, mask);
      ps1 += __shfl_xor(ps1, mask);
      ps2 += __shfl_xor(ps2, mask);
      ps3 += __shfl_xor(ps3, mask);
      pd0 += __shfl_xor(pd0, mask);
      pd1 += __shfl_xor(pd1, mask);
      pd2 += __shfl_xor(pd2, mask);
      pd3 += __shfl_xor(pd3, mask);
    }
    float tS = (wr == 0) ? ps0 : (wr == 1) ? ps1 : (wr == 2) ? ps2 : ps3;
    float tD = (wr == 0) ? pd0 : (wr == 1) ? pd1 : (wr == 2) ? pd2 : pd3;
    if (h == wh) { vS = tS; vD = tD; }
  }
  size_t o = (size_t)(rbase + wr) * 4 + wh;
  AS[o] = vS;
  AD[o] = vD;
}

// ---- fused gather-aggregate + softmax + epilogue, 4-wide unrolled -------
__global__ __launch_bounds__(256) void k_agg(
    const int* __restrict__ row_ptr, const int* __restrict__ deg,
    const int* __restrict__ csr_src,
    const __half* __restrict__ H,
    const float* __restrict__ AS, const float* __restrict__ AD,
    const void* __restrict__ b, void* __restrict__ Y,
    const int* __restrict__ flags, int layer)
{
  int tid = threadIdx.x;
  int node = blockIdx.x * 4 + (tid >> 6);
  if (node >= N_NODES) return;
  int lane = tid & 63;
  int h = lane >> 4;
  int c0 = 2 * lane;
  float adh = AD[(size_t)node * 4 + h];
  int start = row_ptr[node];
  int dg = deg[node];
  const __half2* __restrict__ H2 = (const __half2*)H;
  float accx = 0.f, accy = 0.f, den = 0.f;
  int j = 0;
  for (; j + 4 <= dg; j += 4) {
    int s0 = csr_src[start + j];
    int s1 = csr_src[start + j + 1];
    int s2 = csr_src[start + j + 2];
    int s3 = csr_src[start + j + 3];
    float e0 = AS[(size_t)s0 * 4 + h] + adh;
    float e1 = AS[(size_t)s1 * 4 + h] + adh;
    float e2 = AS[(size_t)s2 * 4 + h] + adh;
    float e3 = AS[(size_t)s3 * 4 + h] + adh;
    float2 v0 = __half22float2(H2[(size_t)s0 * 64 + lane]);
    float2 v1 = __half22float2(H2[(size_t)s1 * 64 + lane]);
    float2 v2 = __half22float2(H2[(size_t)s2 * 64 + lane]);
    float2 v3 = __half22float2(H2[(size_t)s3 * 64 + lane]);
    e0 = e0 > 0.f ? e0 : 0.2f * e0;
    e1 = e1 > 0.f ? e1 : 0.2f * e1;
    e2 = e2 > 0.f ? e2 : 0.2f * e2;
    e3 = e3 > 0.f ? e3 : 0.2f * e3;
    float x0 = __expf(e0), x1 = __expf(e1), x2 = __expf(e2), x3 = __expf(e3);
    accx += x0 * v0.x + x1 * v1.x + x2 * v2.x + x3 * v3.x;
    accy += x0 * v0.y + x1 * v1.y + x2 * v2.y + x3 * v3.y;
    den  += x0 + x1 + x2 + x3;
  }
  for (; j < dg; j++) {
    int s = csr_src[start + j];
    float e = AS[(size_t)s * 4 + h] + adh;
    float2 v = __half22float2(H2[(size_t)s * 64 + lane]);
    e = e > 0.f ? e : 0.2f * e;
    float ex = __expf(e);
    accx += ex * v.x;
    accy += ex * v.y;
    den  += ex;
  }
  float inv = 1.f / (den + 1e-16f);
  int f32 = flags[0];
  float b0 = f32 ? ((const float*)b)[c0]     : bf2f(((const unsigned short*)b)[c0]);
  float b1 = f32 ? ((const float*)b)[c0 + 1] : bf2f(((const unsigned short*)b)[c0 + 1]);
  float r0 = accx * inv + b0;
  float r1 = accy * inv + b1;
  size_t o = (size_t)node * CH + c0;
  if (layer == 1) {                 // relu + bf16 -> X2
    r0 = r0 > 0.f ? r0 : 0.f;
    r1 = r1 > 0.f ? r1 : 0.f;
    ushort2 w; w.x = f2bf(r0); w.y = f2bf(r1);
    *(ushort2*)((unsigned short*)Y + o) = w;
  } else if (f32) {
    float2 w; w.x = r0; w.y = r1;
    *(float2*)((float*)Y + o) = w;
  } else {
    ushort2 w; w.x = f2bf(r0); w.y = f2bf(r1);
    *(ushort2*)((unsigned short*)Y + o) = w;
  }
}

extern "C" void kernel_launch(void* const* d_in, const int* in_sizes, int n_in,
                              void* d_out, int out_size, void* d_ws, size_t ws_size,
                              hipStream_t stream)
{
  const void* x   = d_in[0];
  const int*  ei  = (const int*)d_in[1];
  const void* W1  = d_in[2];
  const void* as1 = d_in[3];
  const void* ad1 = d_in[4];
  const void* b1  = d_in[5];
  const void* W2  = d_in[6];
  const void* as2 = d_in[7];
  const void* ad2 = d_in[8];
  const void* b2  = d_in[9];

  char* ws = (char*)d_ws;
  unsigned short* H  = (unsigned short*)(ws);            // 12,800,000 B (fp16)
  float*  AS         = (float*)(ws + 12800000);          //    800,000 B
  float*  AD         = (float*)(ws + 13600000);          //    800,000 B
  unsigned short* X2 = (unsigned short*)(ws + 14400000); // 12,800,000 B
  int*    deg        = (int*)(ws + 27200000);            //    200,000 B
  int*    row_ptr    = (int*)(ws + 27400064);            //    200,064 B
  int*    cursor     = (int*)(ws + 27600128);            //    200,000 B
  int*    csr_src    = (int*)(ws + 27800128);            //  2,760,000 B
  int*    flags      = (int*)(ws + 30560128);            //         64 B
  int*    bsum       = (int*)(ws + 30560256);            //       1024 B

  const int gemm_blocks  = 3125 / 4 + 1;
  const int edge_blocks  = (E_TOT + 255) / 256;
  const int agg_blocks   = (N_NODES + 3) / 4;            // 1 wave per node

  k_detect<<<1, 256, 0, stream>>>((const unsigned short*)x,
                                  (const unsigned int*)ei, flags);

  // ---- CSR build (shared by both layers) ----
  hipMemsetAsync(deg, 0, (size_t)N_NODES * sizeof(int), stream);
  k_count<<<edge_blocks, 256, 0, stream>>>(ei, deg, flags);
  k_scan1<<<SCAN_NB, 256, 0, stream>>>(deg, row_ptr, bsum);
  k_scan2<<<1, 256, 0, stream>>>(bsum);
  k_scan3<<<SCAN_NB, 256, 0, stream>>>(row_ptr, bsum, cursor);
  k_fill <<<edge_blocks, 256, 0, stream>>>(ei, cursor, csr_src, flags);

  // ---- layer 1 ----
  k_gemm<<<gemm_blocks, 256, 0, stream>>>(x, W1, as1, ad1, H, AS, AD,
                                          N_NODES, flags, 0);
  k_agg <<<agg_blocks,  256, 0, stream>>>(row_ptr, deg, csr_src,
                                          (const __half*)H, AS, AD,
                                          b1, X2, flags, 1);

  // ---- layer 2 ----
  k_gemm<<<gemm_blocks, 256, 0, stream>>>(X2, W2, as2, ad2, H, AS, AD,
                                          N_NODES, flags, 1);
  k_agg <<<agg_blocks,  256, 0, stream>>>(row_ptr, deg, csr_src,
                                          (const __half*)H, AS, AD,
                                          b2, d_out, flags, 2);
}

// Round 8
// 259.003 us; speedup vs baseline: 1.3535x; 1.1991x over previous
//
#include <hip/hip_runtime.h>
#include <hip/hip_bf16.h>
#include <hip/hip_fp16.h>

#define N_NODES 50000
#define N_EDGES 640000
#define E_TOT   690000   // edges + self-loops
#define CH      128
#define SCAN_NB ((N_NODES + 255) / 256)   // 196 scan blocks
#define GEMMB   782                       // 3125 row-tiles / 4 waves, +1
#define EDGEB   ((E_TOT + 255) / 256)     // 2696 edge blocks

typedef __attribute__((ext_vector_type(8))) short short8;
typedef __attribute__((ext_vector_type(4))) float float4v;

static __device__ __forceinline__ float bf2f(unsigned short u) {
  return __uint_as_float(((unsigned)u) << 16);
}
static __device__ __forceinline__ unsigned short f2bf(float f) {
  unsigned u = __float_as_uint(f);
  return (unsigned short)((u + 0x7fffu + ((u >> 16) & 1u)) >> 16);
}

// ---- runtime dtype detection (parallel, 1 block) ------------------------
__global__ void k_detect(const unsigned short* __restrict__ x16,
                         const unsigned int* __restrict__ eiw,
                         int* __restrict__ flags)
{
  __shared__ int sf32, si64;
  int t = threadIdx.x;
  if (t == 0) { sf32 = 0; si64 = 1; }
  __syncthreads();
  int bad = 0;
  for (int i = t; i < 4096; i += 256) {
    float v = bf2f(x16[i]);
    if (!(v == v) || fabsf(v) > 100.f) bad = 1;
  }
  if (bad) atomicOr(&sf32, 1);
  if (t < 128 && eiw[2 * t + 1] != 0u) atomicAnd(&si64, 0);
  __syncthreads();
  if (t == 0) { flags[0] = sf32; flags[1] = si64; }
}

static __device__ __forceinline__ void load_edge(const int* __restrict__ ei,
                                                 int e, int i64, int& s, int& d)
{
  if (e >= N_EDGES) { s = d = e - N_EDGES; return; }
  if (i64) { s = ei[2 * (size_t)e]; d = ei[2 * ((size_t)N_EDGES + e)]; }
  else     { s = ei[e];             d = ei[N_EDGES + e]; }
}

static __device__ __forceinline__ short8 load_bf8(const void* __restrict__ X,
                                                  size_t off, int f32)
{
  if (!f32) return *(const short8*)((const unsigned short*)X + off);
  const float4* p = (const float4*)((const float*)X + off);
  float4 u = p[0], v = p[1];
  short8 r;
  r[0] = (short)f2bf(u.x); r[1] = (short)f2bf(u.y);
  r[2] = (short)f2bf(u.z); r[3] = (short)f2bf(u.w);
  r[4] = (short)f2bf(v.x); r[5] = (short)f2bf(v.y);
  r[6] = (short)f2bf(v.z); r[7] = (short)f2bf(v.w);
  return r;
}

// ---- shared GEMM body (bf16 MFMA 16x16x32, fused alpha epilogue) --------
struct SmemG {
  short Wt[CH][CH + 8];
  float ss[CH], sd[CH];
};

static __device__ __forceinline__ void gemm_body(
    SmemG& sm, int bx,
    const void* __restrict__ X, const void* __restrict__ W,
    const void* __restrict__ a_src, const void* __restrict__ a_dst,
    unsigned short* __restrict__ H, float* __restrict__ AS,
    float* __restrict__ AD, int nrows, int f32, int xf32)
{
  int tid = threadIdx.x;
  if (tid < CH) {
    sm.ss[tid] = f32 ? ((const float*)a_src)[tid] : bf2f(((const unsigned short*)a_src)[tid]);
    sm.sd[tid] = f32 ? ((const float*)a_dst)[tid] : bf2f(((const unsigned short*)a_dst)[tid]);
  }
#pragma unroll
  for (int i = 0; i < (CH * CH) / 256; i++) {
    int idx = tid + i * 256;
    int k = idx >> 7, c = idx & 127;
    sm.Wt[c][k] = f32 ? (short)f2bf(((const float*)W)[idx])
                      : (short)((const unsigned short*)W)[idx];
  }
  __syncthreads();
  int wave = tid >> 6, lane = tid & 63;
  int rt = bx * 4 + wave;
  if (rt * 16 >= nrows) return;
  int R0 = rt * 16;
  int m = lane & 15, quad = lane >> 4;
  size_t abase = (size_t)(R0 + m) * CH + quad * 8;
  float4v acc[8];
#pragma unroll
  for (int t = 0; t < 8; t++) acc[t] = (float4v){0.f, 0.f, 0.f, 0.f};
#pragma unroll
  for (int kb = 0; kb < 4; kb++) {
    short8 a = load_bf8(X, abase + kb * 32, xf32);
#pragma unroll
    for (int ct = 0; ct < 8; ct++) {
      short8 b = *(const short8*)&sm.Wt[ct * 16 + m][kb * 32 + quad * 8];
      acc[ct] = __builtin_amdgcn_mfma_f32_16x16x32_bf16(a, b, acc[ct], 0, 0, 0);
    }
  }
  // H store: direct 2B stores (C/D layout col=ct*16+m, row=quad*4+r)
  int rbase = R0 + quad * 4;
#pragma unroll
  for (int ct = 0; ct < 8; ct++) {
    int col = ct * 16 + m;
#pragma unroll
    for (int r = 0; r < 4; r++)
      H[(size_t)(rbase + r) * CH + col] = __half_as_ushort(__float2half(acc[ct][r]));
  }
  // fused alpha, per-head to keep live state small (r6: spill = 40MB WRITE)
  int wh = m >> 2, wr = m & 3;
  float vS = 0.f, vD = 0.f;
#pragma unroll
  for (int h = 0; h < 4; h++) {
    int ca = 2 * h, cb = 2 * h + 1;
    float sa = sm.ss[ca * 16 + m], sb = sm.ss[cb * 16 + m];
    float da = sm.sd[ca * 16 + m], db = sm.sd[cb * 16 + m];
    float ps0 = acc[ca][0] * sa + acc[cb][0] * sb;
    float ps1 = acc[ca][1] * sa + acc[cb][1] * sb;
    float ps2 = acc[ca][2] * sa + acc[cb][2] * sb;
    float ps3 = acc[ca][3] * sa + acc[cb][3] * sb;
    float pd0 = acc[ca][0] * da + acc[cb][0] * db;
    float pd1 = acc[ca][1] * da + acc[cb][1] * db;
    float pd2 = acc[ca][2] * da + acc[cb][2] * db;
    float pd3 = acc[ca][3] * da + acc[cb][3] * db;
#pragma unroll
    for (int mask = 1; mask < 16; mask <<= 1) {
      ps0 += __shfl_xor(ps0, mask);
      ps1 += __shfl_xor(ps1, mask);
      ps2 += __shfl_xor(ps2, mask);
      ps3 += __shfl_xor(ps3, mask);
      pd0 += __shfl_xor(pd0, mask);
      pd1 += __shfl_xor(pd1, mask);
      pd2 += __shfl_xor(pd2, mask);
      pd3 += __shfl_xor(pd3, mask);
    }
    float tS = (wr == 0) ? ps0 : (wr == 1) ? ps1 : (wr == 2) ? ps2 : ps3;
    float tD = (wr == 0) ? pd0 : (wr == 1) ? pd1 : (wr == 2) ? pd2 : pd3;
    if (h == wh) { vS = tS; vD = tD; }
  }
  size_t o = (size_t)(rbase + wr) * 4 + wh;
  AS[o] = vS;
  AD[o] = vD;
}

// layer-2 GEMM (standalone)
__global__ __launch_bounds__(256, 2) void k_gemm(
    const void* __restrict__ X, const void* __restrict__ W,
    const void* __restrict__ a_src, const void* __restrict__ a_dst,
    unsigned short* __restrict__ H, float* __restrict__ AS, float* __restrict__ AD,
    int nrows, const int* __restrict__ flags, int xmode)
{
  __shared__ SmemG sm;
  int f32 = flags[0];
  gemm_body(sm, blockIdx.x, X, W, a_src, a_dst, H, AS, AD, nrows,
            f32, xmode ? 0 : f32);
}

// layer-1 GEMM fused with CSR count: blocks >= GEMMB run the count pass
// (rank[e] = old deg = edge's slot within its dst segment -> fill needs
// no atomics). GEMM MFMA and count's EA atomics use disjoint pipes.
__global__ __launch_bounds__(256, 2) void k_gemm_count(
    const void* __restrict__ X, const void* __restrict__ W,
    const void* __restrict__ a_src, const void* __restrict__ a_dst,
    unsigned short* __restrict__ H, float* __restrict__ AS, float* __restrict__ AD,
    int nrows, const int* __restrict__ ei, int* __restrict__ deg,
    int* __restrict__ rank, const int* __restrict__ flags)
{
  __shared__ SmemG sm;
  if (blockIdx.x >= GEMMB) {
    int e = (blockIdx.x - GEMMB) * 256 + threadIdx.x;
    if (e < E_TOT) {
      int s, d;
      load_edge(ei, e, flags[1], s, d);
      rank[e] = atomicAdd(&deg[d], 1);
    }
    return;
  }
  int f32 = flags[0];
  gemm_body(sm, blockIdx.x, X, W, a_src, a_dst, H, AS, AD, nrows, f32, f32);
}

// ---- scan (3-kernel grid-wide) ------------------------------------------
__global__ __launch_bounds__(256) void k_scan1(
    const int* __restrict__ deg, int* __restrict__ row_ptr,
    int* __restrict__ bsum)
{
  __shared__ int sh[256];
  int t = threadIdx.x, g = blockIdx.x * 256 + t;
  int v = (g < N_NODES) ? deg[g] : 0;
  sh[t] = v;
  __syncthreads();
  for (int off = 1; off < 256; off <<= 1) {
    int u = (t >= off) ? sh[t - off] : 0;
    __syncthreads();
    sh[t] += u;
    __syncthreads();
  }
  if (g < N_NODES) row_ptr[g] = sh[t] - v;
  if (t == 255) bsum[blockIdx.x] = sh[255];
}

__global__ __launch_bounds__(256) void k_scan2(int* __restrict__ bsum)
{
  __shared__ int sh[256];
  int t = threadIdx.x;
  int v = (t < SCAN_NB) ? bsum[t] : 0;
  sh[t] = v;
  __syncthreads();
  for (int off = 1; off < 256; off <<= 1) {
    int u = (t >= off) ? sh[t - off] : 0;
    __syncthreads();
    sh[t] += u;
    __syncthreads();
  }
  if (t < SCAN_NB) bsum[t] = sh[t] - v;
}

__global__ __launch_bounds__(256) void k_scan3(
    int* __restrict__ row_ptr, const int* __restrict__ bsum)
{
  int g = blockIdx.x * 256 + threadIdx.x;
  if (g >= N_NODES) return;
  row_ptr[g] += bsum[blockIdx.x];
}

// ---- fill: NO atomics — slot = row_ptr[d] + rank[e] ---------------------
__global__ __launch_bounds__(256) void k_fill(
    const int* __restrict__ ei, const int* __restrict__ row_ptr,
    const int* __restrict__ rank, int* __restrict__ csr_src,
    const int* __restrict__ flags)
{
  int e = blockIdx.x * 256 + threadIdx.x;
  if (e >= E_TOT) return;
  int s, d;
  load_edge(ei, e, flags[1], s, d);
  csr_src[row_ptr[d] + rank[e]] = s;
}

// ---- fused gather-aggregate + softmax + epilogue, 8/4-wide MLP ----------
__global__ __launch_bounds__(256) void k_agg(
    const int* __restrict__ row_ptr, const int* __restrict__ deg,
    const int* __restrict__ csr_src,
    const __half* __restrict__ H,
    const float* __restrict__ AS, const float* __restrict__ AD,
    const void* __restrict__ b, void* __restrict__ Y,
    const int* __restrict__ flags, int layer)
{
  int tid = threadIdx.x;
  int node = blockIdx.x * 4 + (tid >> 6);
  if (node >= N_NODES) return;
  int lane = tid & 63;
  int h = lane >> 4;
  int c0 = 2 * lane;
  float adh = AD[(size_t)node * 4 + h];
  int start = row_ptr[node];
  int dg = deg[node];
  const __half2* __restrict__ H2 = (const __half2*)H;
  float accx = 0.f, accy = 0.f, den = 0.f;
  int j = 0;
  for (; j + 8 <= dg; j += 8) {
    int sI[8];
#pragma unroll
    for (int u = 0; u < 8; u++) sI[u] = csr_src[start + j + u];
    float eV[8];
#pragma unroll
    for (int u = 0; u < 8; u++) eV[u] = AS[(size_t)sI[u] * 4 + h] + adh;
    float2 vV[8];
#pragma unroll
    for (int u = 0; u < 8; u++) vV[u] = __half22float2(H2[(size_t)sI[u] * 64 + lane]);
#pragma unroll
    for (int u = 0; u < 8; u++) {
      float x = eV[u] > 0.f ? eV[u] : 0.2f * eV[u];
      float ex = __expf(x);
      accx += ex * vV[u].x;
      accy += ex * vV[u].y;
      den  += ex;
    }
  }
  for (; j + 4 <= dg; j += 4) {
    int sI[4];
#pragma unroll
    for (int u = 0; u < 4; u++) sI[u] = csr_src[start + j + u];
    float eV[4];
#pragma unroll
    for (int u = 0; u < 4; u++) eV[u] = AS[(size_t)sI[u] * 4 + h] + adh;
    float2 vV[4];
#pragma unroll
    for (int u = 0; u < 4; u++) vV[u] = __half22float2(H2[(size_t)sI[u] * 64 + lane]);
#pragma unroll
    for (int u = 0; u < 4; u++) {
      float x = eV[u] > 0.f ? eV[u] : 0.2f * eV[u];
      float ex = __expf(x);
      accx += ex * vV[u].x;
      accy += ex * vV[u].y;
      den  += ex;
    }
  }
  for (; j < dg; j++) {
    int s = csr_src[start + j];
    float e = AS[(size_t)s * 4 + h] + adh;
    float2 v = __half22float2(H2[(size_t)s * 64 + lane]);
    e = e > 0.f ? e : 0.2f * e;
    float ex = __expf(e);
    accx += ex * v.x;
    accy += ex * v.y;
    den  += ex;
  }
  float inv = 1.f / (den + 1e-16f);
  int f32 = flags[0];
  float b0 = f32 ? ((const float*)b)[c0]     : bf2f(((const unsigned short*)b)[c0]);
  float b1 = f32 ? ((const float*)b)[c0 + 1] : bf2f(((const unsigned short*)b)[c0 + 1]);
  float r0 = accx * inv + b0;
  float r1 = accy * inv + b1;
  size_t o = (size_t)node * CH + c0;
  if (layer == 1) {                 // relu + bf16 -> X2
    r0 = r0 > 0.f ? r0 : 0.f;
    r1 = r1 > 0.f ? r1 : 0.f;
    ushort2 w; w.x = f2bf(r0); w.y = f2bf(r1);
    *(ushort2*)((unsigned short*)Y + o) = w;
  } else if (f32) {
    float2 w; w.x = r0; w.y = r1;
    *(float2*)((float*)Y + o) = w;
  } else {
    ushort2 w; w.x = f2bf(r0); w.y = f2bf(r1);
    *(ushort2*)((unsigned short*)Y + o) = w;
  }
}

extern "C" void kernel_launch(void* const* d_in, const int* in_sizes, int n_in,
                              void* d_out, int out_size, void* d_ws, size_t ws_size,
                              hipStream_t stream)
{
  const void* x   = d_in[0];
  const int*  ei  = (const int*)d_in[1];
  const void* W1  = d_in[2];
  const void* as1 = d_in[3];
  const void* ad1 = d_in[4];
  const void* b1  = d_in[5];
  const void* W2  = d_in[6];
  const void* as2 = d_in[7];
  const void* ad2 = d_in[8];
  const void* b2  = d_in[9];

  char* ws = (char*)d_ws;
  unsigned short* H  = (unsigned short*)(ws);            // 12,800,000 B (fp16)
  float*  AS         = (float*)(ws + 12800000);          //    800,000 B
  float*  AD         = (float*)(ws + 13600000);          //    800,000 B
  unsigned short* X2 = (unsigned short*)(ws + 14400000); // 12,800,000 B
  int*    deg        = (int*)(ws + 27200000);            //    200,000 B
  int*    row_ptr    = (int*)(ws + 27400064);            //    200,064 B
  int*    rank       = (int*)(ws + 27600128);            //  2,760,000 B
  int*    csr_src    = (int*)(ws + 30360128);            //  2,760,000 B
  int*    flags      = (int*)(ws + 33120128);            //         64 B
  int*    bsum       = (int*)(ws + 33120256);            //       1024 B

  const int agg_blocks = (N_NODES + 3) / 4;              // 1 wave per node

  k_detect<<<1, 256, 0, stream>>>((const unsigned short*)x,
                                  (const unsigned int*)ei, flags);
  hipMemsetAsync(deg, 0, (size_t)N_NODES * sizeof(int), stream);

  // ---- layer-1 GEMM overlapped with CSR count ----
  k_gemm_count<<<GEMMB + EDGEB, 256, 0, stream>>>(
      x, W1, as1, ad1, H, AS, AD, N_NODES, ei, deg, rank, flags);

  // ---- CSR finalize ----
  k_scan1<<<SCAN_NB, 256, 0, stream>>>(deg, row_ptr, bsum);
  k_scan2<<<1, 256, 0, stream>>>(bsum);
  k_scan3<<<SCAN_NB, 256, 0, stream>>>(row_ptr, bsum);
  k_fill <<<EDGEB, 256, 0, stream>>>(ei, row_ptr, rank, csr_src, flags);

  // ---- layer 1 aggregate ----
  k_agg<<<agg_blocks, 256, 0, stream>>>(row_ptr, deg, csr_src,
                                        (const __half*)H, AS, AD,
                                        b1, X2, flags, 1);

  // ---- layer 2 ----
  k_gemm<<<GEMMB, 256, 0, stream>>>(X2, W2, as2, ad2, H, AS, AD,
                                    N_NODES, flags, 1);
  k_agg<<<agg_blocks, 256, 0, stream>>>(row_ptr, deg, csr_src,
                                        (const __half*)H, AS, AD,
                                        b2, d_out, flags, 2);
}

// Round 9
// 255.908 us; speedup vs baseline: 1.3699x; 1.0121x over previous
//
#include <hip/hip_runtime.h>
#include <hip/hip_bf16.h>
#include <hip/hip_fp16.h>

#define N_NODES 50000
#define N_EDGES 640000
#define E_TOT   690000   // edges + self-loops
#define CH      128
#define GEMMB   782                       // 3125 row-tiles / 4 waves, +1
#define EBLK    2048                      // edges per hist/bucket block
#define NEB     337                       // ceil(E_TOT / EBLK)
#define NBUCK   196                       // ceil(N_NODES / 256)
#define MTP     344                       // MT row pitch (>= NEB)

typedef __attribute__((ext_vector_type(8))) short short8;
typedef __attribute__((ext_vector_type(4))) float float4v;

static __device__ __forceinline__ float bf2f(unsigned short u) {
  return __uint_as_float(((unsigned)u) << 16);
}
static __device__ __forceinline__ unsigned short f2bf(float f) {
  unsigned u = __float_as_uint(f);
  return (unsigned short)((u + 0x7fffu + ((u >> 16) & 1u)) >> 16);
}

// ---- runtime dtype detection (parallel, 1 block) ------------------------
__global__ void k_detect(const unsigned short* __restrict__ x16,
                         const unsigned int* __restrict__ eiw,
                         int* __restrict__ flags)
{
  __shared__ int sf32, si64;
  int t = threadIdx.x;
  if (t == 0) { sf32 = 0; si64 = 1; }
  __syncthreads();
  int bad = 0;
  for (int i = t; i < 4096; i += 256) {
    float v = bf2f(x16[i]);
    if (!(v == v) || fabsf(v) > 100.f) bad = 1;
  }
  if (bad) atomicOr(&sf32, 1);
  if (t < 128 && eiw[2 * t + 1] != 0u) atomicAnd(&si64, 0);
  __syncthreads();
  if (t == 0) { flags[0] = sf32; flags[1] = si64; }
}

static __device__ __forceinline__ void load_edge(const int* __restrict__ ei,
                                                 int e, int i64, int& s, int& d)
{
  if (e >= N_EDGES) { s = d = e - N_EDGES; return; }
  if (i64) { s = ei[2 * (size_t)e]; d = ei[2 * ((size_t)N_EDGES + e)]; }
  else     { s = ei[e];             d = ei[N_EDGES + e]; }
}

static __device__ __forceinline__ short8 load_bf8(const void* __restrict__ X,
                                                  size_t off, int f32)
{
  if (!f32) return *(const short8*)((const unsigned short*)X + off);
  const float4* p = (const float4*)((const float*)X + off);
  float4 u = p[0], v = p[1];
  short8 r;
  r[0] = (short)f2bf(u.x); r[1] = (short)f2bf(u.y);
  r[2] = (short)f2bf(u.z); r[3] = (short)f2bf(u.w);
  r[4] = (short)f2bf(v.x); r[5] = (short)f2bf(v.y);
  r[6] = (short)f2bf(v.z); r[7] = (short)f2bf(v.w);
  return r;
}

// ---- shared GEMM body (bf16 MFMA 16x16x32, fused alpha epilogue) --------
struct SmemG {
  short Wt[CH][CH + 8];
  float ss[CH], sd[CH];
};

static __device__ __forceinline__ void gemm_body(
    SmemG& sm, int bx,
    const void* __restrict__ X, const void* __restrict__ W,
    const void* __restrict__ a_src, const void* __restrict__ a_dst,
    unsigned short* __restrict__ H, float* __restrict__ AS,
    float* __restrict__ AD, int nrows, int f32, int xf32)
{
  int tid = threadIdx.x;
  if (tid < CH) {
    sm.ss[tid] = f32 ? ((const float*)a_src)[tid] : bf2f(((const unsigned short*)a_src)[tid]);
    sm.sd[tid] = f32 ? ((const float*)a_dst)[tid] : bf2f(((const unsigned short*)a_dst)[tid]);
  }
#pragma unroll
  for (int i = 0; i < (CH * CH) / 256; i++) {
    int idx = tid + i * 256;
    int k = idx >> 7, c = idx & 127;
    sm.Wt[c][k] = f32 ? (short)f2bf(((const float*)W)[idx])
                      : (short)((const unsigned short*)W)[idx];
  }
  __syncthreads();
  int wave = tid >> 6, lane = tid & 63;
  int rt = bx * 4 + wave;
  if (rt * 16 >= nrows) return;
  int R0 = rt * 16;
  int m = lane & 15, quad = lane >> 4;
  size_t abase = (size_t)(R0 + m) * CH + quad * 8;
  float4v acc[8];
#pragma unroll
  for (int t = 0; t < 8; t++) acc[t] = (float4v){0.f, 0.f, 0.f, 0.f};
#pragma unroll
  for (int kb = 0; kb < 4; kb++) {
    short8 a = load_bf8(X, abase + kb * 32, xf32);
#pragma unroll
    for (int ct = 0; ct < 8; ct++) {
      short8 b = *(const short8*)&sm.Wt[ct * 16 + m][kb * 32 + quad * 8];
      acc[ct] = __builtin_amdgcn_mfma_f32_16x16x32_bf16(a, b, acc[ct], 0, 0, 0);
    }
  }
  // H store (C/D layout col=ct*16+m, row=quad*4+r)
  int rbase = R0 + quad * 4;
#pragma unroll
  for (int ct = 0; ct < 8; ct++) {
    int col = ct * 16 + m;
#pragma unroll
    for (int r = 0; r < 4; r++)
      H[(size_t)(rbase + r) * CH + col] = __half_as_ushort(__float2half(acc[ct][r]));
  }
  // fused alpha, per-head to keep live state small (r6: spill lesson)
  int wh = m >> 2, wr = m & 3;
  float vS = 0.f, vD = 0.f;
#pragma unroll
  for (int h = 0; h < 4; h++) {
    int ca = 2 * h, cb = 2 * h + 1;
    float sa = sm.ss[ca * 16 + m], sb = sm.ss[cb * 16 + m];
    float da = sm.sd[ca * 16 + m], db = sm.sd[cb * 16 + m];
    float ps0 = acc[ca][0] * sa + acc[cb][0] * sb;
    float ps1 = acc[ca][1] * sa + acc[cb][1] * sb;
    float ps2 = acc[ca][2] * sa + acc[cb][2] * sb;
    float ps3 = acc[ca][3] * sa + acc[cb][3] * sb;
    float pd0 = acc[ca][0] * da + acc[cb][0] * db;
    float pd1 = acc[ca][1] * da + acc[cb][1] * db;
    float pd2 = acc[ca][2] * da + acc[cb][2] * db;
    float pd3 = acc[ca][3] * da + acc[cb][3] * db;
#pragma unroll
    for (int mask = 1; mask < 16; mask <<= 1) {
      ps0 += __shfl_xor(ps0, mask);
      ps1 += __shfl_xor(ps1, mask);
      ps2 += __shfl_xor(ps2, mask);
      ps3 += __shfl_xor(ps3, mask);
      pd0 += __shfl_xor(pd0, mask);
      pd1 += __shfl_xor(pd1, mask);
      pd2 += __shfl_xor(pd2, mask);
      pd3 += __shfl_xor(pd3, mask);
    }
    float tS = (wr == 0) ? ps0 : (wr == 1) ? ps1 : (wr == 2) ? ps2 : ps3;
    float tD = (wr == 0) ? pd0 : (wr == 1) ? pd1 : (wr == 2) ? pd2 : pd3;
    if (h == wh) { vS = tS; vD = tD; }
  }
  size_t o = (size_t)(rbase + wr) * 4 + wh;
  AS[o] = vS;
  AD[o] = vD;
}

// layer-2 GEMM (standalone)
__global__ __launch_bounds__(256, 2) void k_gemm(
    const void* __restrict__ X, const void* __restrict__ W,
    const void* __restrict__ a_src, const void* __restrict__ a_dst,
    unsigned short* __restrict__ H, float* __restrict__ AS, float* __restrict__ AD,
    int nrows, const int* __restrict__ flags, int xmode)
{
  __shared__ SmemG sm;
  int f32 = flags[0];
  gemm_body(sm, blockIdx.x, X, W, a_src, a_dst, H, AS, AD, nrows,
            f32, xmode ? 0 : f32);
}

// layer-1 GEMM fused with bucket histogram (pass A): blocks >= GEMMB build
// MT[q][b] = #edges of edge-block b whose dst is in bucket q (dst>>8).
// LDS-aggregated -> ZERO global atomics (r8: 690k device atomics = 47us).
__global__ __launch_bounds__(256, 2) void k_gemm_hist(
    const void* __restrict__ X, const void* __restrict__ W,
    const void* __restrict__ a_src, const void* __restrict__ a_dst,
    unsigned short* __restrict__ H, float* __restrict__ AS, float* __restrict__ AD,
    int nrows, const int* __restrict__ ei, int* __restrict__ MT,
    const int* __restrict__ flags)
{
  __shared__ SmemG sm;          // gemm blocks only
  __shared__ int hist[NBUCK];   // hist blocks only
  if (blockIdx.x >= GEMMB) {
    int b = blockIdx.x - GEMMB;
    int t = threadIdx.x;
    if (t < NBUCK) hist[t] = 0;
    __syncthreads();
    int i64 = flags[1];
    int base = b * EBLK;
#pragma unroll
    for (int k = 0; k < 8; k++) {
      int e = base + k * 256 + t;
      if (e < E_TOT) {
        int s, d;
        load_edge(ei, e, i64, s, d);
        atomicAdd(&hist[d >> 8], 1);
      }
    }
    __syncthreads();
    if (t < NBUCK) MT[t * MTP + b] = hist[t];
    return;
  }
  int f32 = flags[0];
  gemm_body(sm, blockIdx.x, X, W, a_src, a_dst, H, AS, AD, nrows, f32, f32);
}

// pass B: exclusive-scan each MT row (per bucket, over edge-blocks); T[q]=total
__global__ __launch_bounds__(512) void k_rowscan(int* __restrict__ MT,
                                                 int* __restrict__ T)
{
  __shared__ int sh[512];
  int q = blockIdx.x, t = threadIdx.x;
  int v = (t < NEB) ? MT[q * MTP + t] : 0;
  sh[t] = v;
  __syncthreads();
  for (int off = 1; off < 512; off <<= 1) {
    int u = (t >= off) ? sh[t - off] : 0;
    __syncthreads();
    sh[t] += u;
    __syncthreads();
  }
  if (t < NEB) MT[q * MTP + t] = sh[t] - v;
  if (t == NEB - 1) T[q] = sh[t];
}

// pass B2: exclusive-scan bucket totals -> BB[0..NBUCK] (BB[NBUCK]=E_TOT)
__global__ __launch_bounds__(256) void k_bscan(const int* __restrict__ T,
                                               int* __restrict__ BB)
{
  __shared__ int sh[256];
  int t = threadIdx.x;
  int v = (t < NBUCK) ? T[t] : 0;
  sh[t] = v;
  __syncthreads();
  for (int off = 1; off < 256; off <<= 1) {
    int u = (t >= off) ? sh[t - off] : 0;
    __syncthreads();
    sh[t] += u;
    __syncthreads();
  }
  if (t < NBUCK) BB[t] = sh[t] - v;
  if (t == NBUCK - 1) BB[NBUCK] = sh[t];
}

// pass C: scatter edges (s,d) into bucket-ordered ebuf. Each (block,bucket)
// range is exclusive -> plain stores, block-private segments (L2-combined).
__global__ __launch_bounds__(256) void k_bucket(
    const int* __restrict__ ei, const int* __restrict__ MT,
    const int* __restrict__ BB, int2* __restrict__ ebuf,
    const int* __restrict__ flags)
{
  __shared__ int cur[NBUCK];
  int b = blockIdx.x, t = threadIdx.x;
  if (t < NBUCK) cur[t] = BB[t] + MT[t * MTP + b];
  __syncthreads();
  int i64 = flags[1];
  int base = b * EBLK;
#pragma unroll
  for (int k = 0; k < 8; k++) {
    int e = base + k * 256 + t;
    if (e < E_TOT) {
      int s, d;
      load_edge(ei, e, i64, s, d);
      int pos = atomicAdd(&cur[d >> 8], 1);   // LDS atomic
      ebuf[pos] = make_int2(s, d);
    }
  }
}

// pass D: per-bucket fine CSR: count(LDS)+scan -> row_ptr/deg directly
// (bucket base + local prefix == global prefix), then scatter csr_src
// within the bucket's private range.
__global__ __launch_bounds__(256) void k_fine(
    const int2* __restrict__ ebuf, const int* __restrict__ BB,
    int* __restrict__ row_ptr, int* __restrict__ deg,
    int* __restrict__ csr_src)
{
  __shared__ int cnt[256], sh[256], cur[256];
  int q = blockIdx.x, t = threadIdx.x;
  int lo = BB[q], hi = BB[q + 1];
  cnt[t] = 0;
  __syncthreads();
  for (int i = lo + t; i < hi; i += 256)
    atomicAdd(&cnt[ebuf[i].y & 255], 1);
  __syncthreads();
  int v = cnt[t];
  sh[t] = v;
  __syncthreads();
  for (int off = 1; off < 256; off <<= 1) {
    int u = (t >= off) ? sh[t - off] : 0;
    __syncthreads();
    sh[t] += u;
    __syncthreads();
  }
  int lp = sh[t] - v;                 // exclusive local prefix
  int n = (q << 8) + t;
  if (n < N_NODES) { row_ptr[n] = lo + lp; deg[n] = v; }
  cur[t] = lo + lp;
  __syncthreads();
  for (int i = lo + t; i < hi; i += 256) {
    int2 p = ebuf[i];
    int slot = atomicAdd(&cur[p.y & 255], 1);   // LDS atomic
    csr_src[slot] = p.x;
  }
}

// ---- fused gather-aggregate + softmax + epilogue, 8/4-wide MLP ----------
__global__ __launch_bounds__(256) void k_agg(
    const int* __restrict__ row_ptr, const int* __restrict__ deg,
    const int* __restrict__ csr_src,
    const __half* __restrict__ H,
    const float* __restrict__ AS, const float* __restrict__ AD,
    const void* __restrict__ b, void* __restrict__ Y,
    const int* __restrict__ flags, int layer)
{
  int tid = threadIdx.x;
  int node = blockIdx.x * 4 + (tid >> 6);
  if (node >= N_NODES) return;
  int lane = tid & 63;
  int h = lane >> 4;
  int c0 = 2 * lane;
  float adh = AD[(size_t)node * 4 + h];
  int start = row_ptr[node];
  int dg = deg[node];
  const __half2* __restrict__ H2 = (const __half2*)H;
  float accx = 0.f, accy = 0.f, den = 0.f;
  int j = 0;
  for (; j + 8 <= dg; j += 8) {
    int sI[8];
#pragma unroll
    for (int u = 0; u < 8; u++) sI[u] = csr_src[start + j + u];
    float eV[8];
#pragma unroll
    for (int u = 0; u < 8; u++) eV[u] = AS[(size_t)sI[u] * 4 + h] + adh;
    float2 vV[8];
#pragma unroll
    for (int u = 0; u < 8; u++) vV[u] = __half22float2(H2[(size_t)sI[u] * 64 + lane]);
#pragma unroll
    for (int u = 0; u < 8; u++) {
      float x = eV[u] > 0.f ? eV[u] : 0.2f * eV[u];
      float ex = __expf(x);
      accx += ex * vV[u].x;
      accy += ex * vV[u].y;
      den  += ex;
    }
  }
  for (; j + 4 <= dg; j += 4) {
    int sI[4];
#pragma unroll
    for (int u = 0; u < 4; u++) sI[u] = csr_src[start + j + u];
    float eV[4];
#pragma unroll
    for (int u = 0; u < 4; u++) eV[u] = AS[(size_t)sI[u] * 4 + h] + adh;
    float2 vV[4];
#pragma unroll
    for (int u = 0; u < 4; u++) vV[u] = __half22float2(H2[(size_t)sI[u] * 64 + lane]);
#pragma unroll
    for (int u = 0; u < 4; u++) {
      float x = eV[u] > 0.f ? eV[u] : 0.2f * eV[u];
      float ex = __expf(x);
      accx += ex * vV[u].x;
      accy += ex * vV[u].y;
      den  += ex;
    }
  }
  for (; j < dg; j++) {
    int s = csr_src[start + j];
    float e = AS[(size_t)s * 4 + h] + adh;
    float2 v = __half22float2(H2[(size_t)s * 64 + lane]);
    e = e > 0.f ? e : 0.2f * e;
    float ex = __expf(e);
    accx += ex * v.x;
    accy += ex * v.y;
    den  += ex;
  }
  float inv = 1.f / (den + 1e-16f);
  int f32 = flags[0];
  float b0 = f32 ? ((const float*)b)[c0]     : bf2f(((const unsigned short*)b)[c0]);
  float b1 = f32 ? ((const float*)b)[c0 + 1] : bf2f(((const unsigned short*)b)[c0 + 1]);
  float r0 = accx * inv + b0;
  float r1 = accy * inv + b1;
  size_t o = (size_t)node * CH + c0;
  if (layer == 1) {                 // relu + bf16 -> X2
    r0 = r0 > 0.f ? r0 : 0.f;
    r1 = r1 > 0.f ? r1 : 0.f;
    ushort2 w; w.x = f2bf(r0); w.y = f2bf(r1);
    *(ushort2*)((unsigned short*)Y + o) = w;
  } else if (f32) {
    float2 w; w.x = r0; w.y = r1;
    *(float2*)((float*)Y + o) = w;
  } else {
    ushort2 w; w.x = f2bf(r0); w.y = f2bf(r1);
    *(ushort2*)((unsigned short*)Y + o) = w;
  }
}

extern "C" void kernel_launch(void* const* d_in, const int* in_sizes, int n_in,
                              void* d_out, int out_size, void* d_ws, size_t ws_size,
                              hipStream_t stream)
{
  const void* x   = d_in[0];
  const int*  ei  = (const int*)d_in[1];
  const void* W1  = d_in[2];
  const void* as1 = d_in[3];
  const void* ad1 = d_in[4];
  const void* b1  = d_in[5];
  const void* W2  = d_in[6];
  const void* as2 = d_in[7];
  const void* ad2 = d_in[8];
  const void* b2  = d_in[9];

  char* ws = (char*)d_ws;
  unsigned short* H  = (unsigned short*)(ws);            // 12,800,000 B (fp16)
  float*  AS         = (float*)(ws + 12800000);          //    800,000 B
  float*  AD         = (float*)(ws + 13600000);          //    800,000 B
  unsigned short* X2 = (unsigned short*)(ws + 14400000); // 12,800,000 B
  int*    deg        = (int*)(ws + 27200000);            //    200,000 B
  int*    row_ptr    = (int*)(ws + 27400000);            //    200,000 B
  int*    csr_src    = (int*)(ws + 27600000);            //  2,760,000 B
  int*    MT         = (int*)(ws + 30360000);            //    269,696 B
  int*    T          = (int*)(ws + 30630000);            //        784 B
  int*    BB         = (int*)(ws + 30631000);            //        788 B
  int*    flags      = (int*)(ws + 30632000);            //         64 B
  int2*   ebuf       = (int2*)(ws + 30640000);           //  5,520,000 B

  const int agg_blocks = (N_NODES + 3) / 4;              // 1 wave per node

  k_detect<<<1, 256, 0, stream>>>((const unsigned short*)x,
                                  (const unsigned int*)ei, flags);

  // ---- layer-1 GEMM overlapped with bucket histogram (pass A) ----
  k_gemm_hist<<<GEMMB + NEB, 256, 0, stream>>>(
      x, W1, as1, ad1, H, AS, AD, N_NODES, ei, MT, flags);

  // ---- CSR build, atomic-free ----
  k_rowscan<<<NBUCK, 512, 0, stream>>>(MT, T);
  k_bscan  <<<1, 256, 0, stream>>>(T, BB);
  k_bucket <<<NEB, 256, 0, stream>>>(ei, MT, BB, ebuf, flags);
  k_fine   <<<NBUCK, 256, 0, stream>>>(ebuf, BB, row_ptr, deg, csr_src);

  // ---- layer 1 aggregate ----
  k_agg<<<agg_blocks, 256, 0, stream>>>(row_ptr, deg, csr_src,
                                        (const __half*)H, AS, AD,
                                        b1, X2, flags, 1);

  // ---- layer 2 ----
  k_gemm<<<GEMMB, 256, 0, stream>>>(X2, W2, as2, ad2, H, AS, AD,
                                    N_NODES, flags, 1);
  k_agg<<<agg_blocks, 256, 0, stream>>>(row_ptr, deg, csr_src,
                                        (const __half*)H, AS, AD,
                                        b2, d_out, flags, 2);
}

// Round 10
// 214.757 us; speedup vs baseline: 1.6324x; 1.1916x over previous
//
#include <hip/hip_runtime.h>
#include <hip/hip_bf16.h>
#include <hip/hip_fp16.h>

#define N_NODES 50000
#define N_EDGES 640000
#define E_TOT   690000   // edges + self-loops
#define CH      128
#define GEMMB   782                       // 3125 row-tiles / 4 waves, +1
#define EBLK    2048                      // edges per hist/bucket block
#define NEB     337                       // ceil(E_TOT / EBLK)
#define NBUCK   196                       // ceil(N_NODES / 256)
#define MTP     344                       // MT row pitch (>= NEB)

typedef __attribute__((ext_vector_type(8))) short short8;
typedef __attribute__((ext_vector_type(4))) float float4v;

static __device__ __forceinline__ float bf2f(unsigned short u) {
  return __uint_as_float(((unsigned)u) << 16);
}
static __device__ __forceinline__ unsigned short f2bf(float f) {
  unsigned u = __float_as_uint(f);
  return (unsigned short)((u + 0x7fffu + ((u >> 16) & 1u)) >> 16);
}

// ---- runtime dtype detection (parallel, 1 block) ------------------------
__global__ void k_detect(const unsigned short* __restrict__ x16,
                         const unsigned int* __restrict__ eiw,
                         int* __restrict__ flags)
{
  __shared__ int sf32, si64;
  int t = threadIdx.x;
  if (t == 0) { sf32 = 0; si64 = 1; }
  __syncthreads();
  int bad = 0;
  for (int i = t; i < 4096; i += 256) {
    float v = bf2f(x16[i]);
    if (!(v == v) || fabsf(v) > 100.f) bad = 1;
  }
  if (bad) atomicOr(&sf32, 1);
  if (t < 128 && eiw[2 * t + 1] != 0u) atomicAnd(&si64, 0);
  __syncthreads();
  if (t == 0) { flags[0] = sf32; flags[1] = si64; }
}

static __device__ __forceinline__ void load_edge(const int* __restrict__ ei,
                                                 int e, int i64, int& s, int& d)
{
  if (e >= N_EDGES) { s = d = e - N_EDGES; return; }
  if (i64) { s = ei[2 * (size_t)e]; d = ei[2 * ((size_t)N_EDGES + e)]; }
  else     { s = ei[e];             d = ei[N_EDGES + e]; }
}

static __device__ __forceinline__ short8 load_bf8(const void* __restrict__ X,
                                                  size_t off, int f32)
{
  if (!f32) return *(const short8*)((const unsigned short*)X + off);
  const float4* p = (const float4*)((const float*)X + off);
  float4 u = p[0], v = p[1];
  short8 r;
  r[0] = (short)f2bf(u.x); r[1] = (short)f2bf(u.y);
  r[2] = (short)f2bf(u.z); r[3] = (short)f2bf(u.w);
  r[4] = (short)f2bf(v.x); r[5] = (short)f2bf(v.y);
  r[6] = (short)f2bf(v.z); r[7] = (short)f2bf(v.w);
  return r;
}

// ---- prep: transpose W -> Wt_g[c][k]; Ba_g[n][k] = sum_c W[k][c]*a[n][c] --
// blocks 0..7: Ba (2 layers x 128 k x 8 n, plus zero rows 8..15)
// blocks 8..263: W transpose (2 layers x 128 cols)
__global__ __launch_bounds__(256) void k_prep(
    const void* __restrict__ W1, const void* __restrict__ W2,
    const void* __restrict__ as1, const void* __restrict__ ad1,
    const void* __restrict__ as2, const void* __restrict__ ad2,
    unsigned short* __restrict__ Wt1, unsigned short* __restrict__ Wt2,
    unsigned short* __restrict__ Ba1, unsigned short* __restrict__ Ba2,
    const int* __restrict__ flags)
{
  int f32 = flags[0];
  int b = blockIdx.x, t = threadIdx.x;
  if (b < 8) {
    int g = b * 256 + t;          // 0..2047
    int l = g >> 10;
    int rem = g & 1023;
    int k = rem >> 3, n = rem & 7;
    const void* W  = l ? W2 : W1;
    const void* av = (n < 4) ? (l ? as2 : as1) : (l ? ad2 : ad1);
    int h = n & 3;
    float sum = 0.f;
    for (int c = 0; c < 32; c++) {
      float w = f32 ? ((const float*)W)[k * 128 + h * 32 + c]
                    : bf2f(((const unsigned short*)W)[k * 128 + h * 32 + c]);
      float a = f32 ? ((const float*)av)[h * 32 + c]
                    : bf2f(((const unsigned short*)av)[h * 32 + c]);
      sum += w * a;
    }
    unsigned short* Ba = l ? Ba2 : Ba1;
    Ba[n * 128 + k] = f2bf(sum);
    Ba[(8 + (rem >> 7)) * 128 + (rem & 127)] = 0;   // zero rows 8..15
  } else {
    int b2 = b - 8;
    int l = b2 >> 7, c = b2 & 127;
    if (t < 128) {
      const void* W = l ? W2 : W1;
      unsigned short* Wt = l ? Wt2 : Wt1;
      Wt[c * 128 + t] = f32 ? f2bf(((const float*)W)[t * 128 + c])
                            : ((const unsigned short*)W)[t * 128 + c];
    }
  }
}

// ---- shared GEMM body: H = X @ W + fused alpha via extra MFMA column ----
// WB rows 0..127: W^T (pitch 136); rows 128..143: Ba^T (AS/AD weights).
// Staging: 9 x (dwordx4 + ds_write_b128) per thread (r9: 64+64 scalar ops
// + 128 shfl epilogue made the gemm issue/latency-bound at 46us).
struct SmemG { unsigned short WB[144][136]; };

static __device__ __forceinline__ void gemm_body(
    SmemG& sm, int bx,
    const void* __restrict__ X,
    const unsigned short* __restrict__ Wt_g,
    const unsigned short* __restrict__ Ba_g,
    unsigned short* __restrict__ H, float* __restrict__ AS,
    float* __restrict__ AD, int nrows, int xf32)
{
  int tid = threadIdx.x;
#pragma unroll
  for (int i = 0; i < 8; i++) {
    int j = i * 256 + tid;        // 2048 16B chunks of W^T
    int c = j >> 4, k8 = j & 15;
    short8 v = *(const short8*)(Wt_g + c * 128 + k8 * 8);
    *(short8*)&sm.WB[c][k8 * 8] = v;
  }
  {
    int n = tid >> 4, k8 = tid & 15;   // Ba rows 128..143 (8..15 zeroed)
    short8 v = *(const short8*)(Ba_g + n * 128 + k8 * 8);
    *(short8*)&sm.WB[128 + n][k8 * 8] = v;
  }
  __syncthreads();
  int wave = tid >> 6, lane = tid & 63;
  int rt = bx * 4 + wave;
  if (rt * 16 >= nrows) return;
  int R0 = rt * 16;
  int m = lane & 15, quad = lane >> 4;
  size_t abase = (size_t)(R0 + m) * CH + quad * 8;
  float4v acc[8];
  float4v accA = (float4v){0.f, 0.f, 0.f, 0.f};
#pragma unroll
  for (int t = 0; t < 8; t++) acc[t] = (float4v){0.f, 0.f, 0.f, 0.f};
#pragma unroll
  for (int kb = 0; kb < 4; kb++) {
    short8 a = load_bf8(X, abase + kb * 32, xf32);
#pragma unroll
    for (int ct = 0; ct < 8; ct++) {
      short8 b = *(const short8*)&sm.WB[ct * 16 + m][kb * 32 + quad * 8];
      acc[ct] = __builtin_amdgcn_mfma_f32_16x16x32_bf16(a, b, acc[ct], 0, 0, 0);
    }
    short8 bA = *(const short8*)&sm.WB[128 + m][kb * 32 + quad * 8];
    accA = __builtin_amdgcn_mfma_f32_16x16x32_bf16(a, bA, accA, 0, 0, 0);
  }
  // H store (C/D layout col=ct*16+m, row=quad*4+r)
  int rbase = R0 + quad * 4;
#pragma unroll
  for (int ct = 0; ct < 8; ct++) {
    int col = ct * 16 + m;
#pragma unroll
    for (int r = 0; r < 4; r++)
      H[(size_t)(rbase + r) * CH + col] = __half_as_ushort(__float2half(acc[ct][r]));
  }
  // alpha store: accA col m = head (0..3 -> AS, 4..7 -> AD), row = quad*4+r
  if (m < 4) {
#pragma unroll
    for (int r = 0; r < 4; r++)
      AS[(size_t)(rbase + r) * 4 + m] = accA[r];
  } else if (m < 8) {
#pragma unroll
    for (int r = 0; r < 4; r++)
      AD[(size_t)(rbase + r) * 4 + (m - 4)] = accA[r];
  }
}

// layer-2 GEMM (standalone; X2 always bf16)
__global__ __launch_bounds__(256, 2) void k_gemm(
    const void* __restrict__ X,
    const unsigned short* __restrict__ Wt_g,
    const unsigned short* __restrict__ Ba_g,
    unsigned short* __restrict__ H, float* __restrict__ AS, float* __restrict__ AD,
    int nrows)
{
  __shared__ SmemG sm;
  gemm_body(sm, blockIdx.x, X, Wt_g, Ba_g, H, AS, AD, nrows, 0);
}

// layer-1 GEMM fused with bucket histogram (pass A)
__global__ __launch_bounds__(256, 2) void k_gemm_hist(
    const void* __restrict__ X,
    const unsigned short* __restrict__ Wt_g,
    const unsigned short* __restrict__ Ba_g,
    unsigned short* __restrict__ H, float* __restrict__ AS, float* __restrict__ AD,
    int nrows, const int* __restrict__ ei, int* __restrict__ MT,
    const int* __restrict__ flags)
{
  __shared__ SmemG sm;          // gemm blocks only
  __shared__ int hist[NBUCK];   // hist blocks only
  if (blockIdx.x >= GEMMB) {
    int b = blockIdx.x - GEMMB;
    int t = threadIdx.x;
    if (t < NBUCK) hist[t] = 0;
    __syncthreads();
    int i64 = flags[1];
    int base = b * EBLK;
#pragma unroll
    for (int k = 0; k < 8; k++) {
      int e = base + k * 256 + t;
      if (e < E_TOT) {
        int s, d;
        load_edge(ei, e, i64, s, d);
        atomicAdd(&hist[d >> 8], 1);
      }
    }
    __syncthreads();
    if (t < NBUCK) MT[t * MTP + b] = hist[t];
    return;
  }
  gemm_body(sm, blockIdx.x, X, Wt_g, Ba_g, H, AS, AD, nrows, flags[0]);
}

// pass B: exclusive-scan each MT row; T[q]=total
__global__ __launch_bounds__(512) void k_rowscan(int* __restrict__ MT,
                                                 int* __restrict__ T)
{
  __shared__ int sh[512];
  int q = blockIdx.x, t = threadIdx.x;
  int v = (t < NEB) ? MT[q * MTP + t] : 0;
  sh[t] = v;
  __syncthreads();
  for (int off = 1; off < 512; off <<= 1) {
    int u = (t >= off) ? sh[t - off] : 0;
    __syncthreads();
    sh[t] += u;
    __syncthreads();
  }
  if (t < NEB) MT[q * MTP + t] = sh[t] - v;
  if (t == NEB - 1) T[q] = sh[t];
}

// pass B2: exclusive-scan bucket totals
__global__ __launch_bounds__(256) void k_bscan(const int* __restrict__ T,
                                               int* __restrict__ BB)
{
  __shared__ int sh[256];
  int t = threadIdx.x;
  int v = (t < NBUCK) ? T[t] : 0;
  sh[t] = v;
  __syncthreads();
  for (int off = 1; off < 256; off <<= 1) {
    int u = (t >= off) ? sh[t - off] : 0;
    __syncthreads();
    sh[t] += u;
    __syncthreads();
  }
  if (t < NBUCK) BB[t] = sh[t] - v;
  if (t == NBUCK - 1) BB[NBUCK] = sh[t];
}

// pass C: scatter edges into bucket-ordered ebuf (LDS cursors)
__global__ __launch_bounds__(256) void k_bucket(
    const int* __restrict__ ei, const int* __restrict__ MT,
    const int* __restrict__ BB, int2* __restrict__ ebuf,
    const int* __restrict__ flags)
{
  __shared__ int cur[NBUCK];
  int b = blockIdx.x, t = threadIdx.x;
  if (t < NBUCK) cur[t] = BB[t] + MT[t * MTP + b];
  __syncthreads();
  int i64 = flags[1];
  int base = b * EBLK;
#pragma unroll
  for (int k = 0; k < 8; k++) {
    int e = base + k * 256 + t;
    if (e < E_TOT) {
      int s, d;
      load_edge(ei, e, i64, s, d);
      int pos = atomicAdd(&cur[d >> 8], 1);   // LDS atomic
      ebuf[pos] = make_int2(s, d);
    }
  }
}

// pass D: per-bucket fine CSR
__global__ __launch_bounds__(256) void k_fine(
    const int2* __restrict__ ebuf, const int* __restrict__ BB,
    int* __restrict__ row_ptr, int* __restrict__ deg,
    int* __restrict__ csr_src)
{
  __shared__ int cnt[256], sh[256], cur[256];
  int q = blockIdx.x, t = threadIdx.x;
  int lo = BB[q], hi = BB[q + 1];
  cnt[t] = 0;
  __syncthreads();
  for (int i = lo + t; i < hi; i += 256)
    atomicAdd(&cnt[ebuf[i].y & 255], 1);
  __syncthreads();
  int v = cnt[t];
  sh[t] = v;
  __syncthreads();
  for (int off = 1; off < 256; off <<= 1) {
    int u = (t >= off) ? sh[t - off] : 0;
    __syncthreads();
    sh[t] += u;
    __syncthreads();
  }
  int lp = sh[t] - v;
  int n = (q << 8) + t;
  if (n < N_NODES) { row_ptr[n] = lo + lp; deg[n] = v; }
  cur[t] = lo + lp;
  __syncthreads();
  for (int i = lo + t; i < hi; i += 256) {
    int2 p = ebuf[i];
    int slot = atomicAdd(&cur[p.y & 255], 1);   // LDS atomic
    csr_src[slot] = p.x;
  }
}

// ---- fused gather-aggregate + softmax + epilogue, 8/4-wide MLP ----------
__global__ __launch_bounds__(256) void k_agg(
    const int* __restrict__ row_ptr, const int* __restrict__ deg,
    const int* __restrict__ csr_src,
    const __half* __restrict__ H,
    const float* __restrict__ AS, const float* __restrict__ AD,
    const void* __restrict__ b, void* __restrict__ Y,
    const int* __restrict__ flags, int layer)
{
  int tid = threadIdx.x;
  int node = blockIdx.x * 4 + (tid >> 6);
  if (node >= N_NODES) return;
  int lane = tid & 63;
  int h = lane >> 4;
  int c0 = 2 * lane;
  float adh = AD[(size_t)node * 4 + h];
  int start = row_ptr[node];
  int dg = deg[node];
  const __half2* __restrict__ H2 = (const __half2*)H;
  float accx = 0.f, accy = 0.f, den = 0.f;
  int j = 0;
  for (; j + 8 <= dg; j += 8) {
    int sI[8];
#pragma unroll
    for (int u = 0; u < 8; u++) sI[u] = csr_src[start + j + u];
    float eV[8];
#pragma unroll
    for (int u = 0; u < 8; u++) eV[u] = AS[(size_t)sI[u] * 4 + h] + adh;
    float2 vV[8];
#pragma unroll
    for (int u = 0; u < 8; u++) vV[u] = __half22float2(H2[(size_t)sI[u] * 64 + lane]);
#pragma unroll
    for (int u = 0; u < 8; u++) {
      float x = eV[u] > 0.f ? eV[u] : 0.2f * eV[u];
      float ex = __expf(x);
      accx += ex * vV[u].x;
      accy += ex * vV[u].y;
      den  += ex;
    }
  }
  for (; j + 4 <= dg; j += 4) {
    int sI[4];
#pragma unroll
    for (int u = 0; u < 4; u++) sI[u] = csr_src[start + j + u];
    float eV[4];
#pragma unroll
    for (int u = 0; u < 4; u++) eV[u] = AS[(size_t)sI[u] * 4 + h] + adh;
    float2 vV[4];
#pragma unroll
    for (int u = 0; u < 4; u++) vV[u] = __half22float2(H2[(size_t)sI[u] * 64 + lane]);
#pragma unroll
    for (int u = 0; u < 4; u++) {
      float x = eV[u] > 0.f ? eV[u] : 0.2f * eV[u];
      float ex = __expf(x);
      accx += ex * vV[u].x;
      accy += ex * vV[u].y;
      den  += ex;
    }
  }
  for (; j < dg; j++) {
    int s = csr_src[start + j];
    float e = AS[(size_t)s * 4 + h] + adh;
    float2 v = __half22float2(H2[(size_t)s * 64 + lane]);
    e = e > 0.f ? e : 0.2f * e;
    float ex = __expf(e);
    accx += ex * v.x;
    accy += ex * v.y;
    den  += ex;
  }
  float inv = 1.f / (den + 1e-16f);
  int f32 = flags[0];
  float b0 = f32 ? ((const float*)b)[c0]     : bf2f(((const unsigned short*)b)[c0]);
  float b1 = f32 ? ((const float*)b)[c0 + 1] : bf2f(((const unsigned short*)b)[c0 + 1]);
  float r0 = accx * inv + b0;
  float r1 = accy * inv + b1;
  size_t o = (size_t)node * CH + c0;
  if (layer == 1) {                 // relu + bf16 -> X2
    r0 = r0 > 0.f ? r0 : 0.f;
    r1 = r1 > 0.f ? r1 : 0.f;
    ushort2 w; w.x = f2bf(r0); w.y = f2bf(r1);
    *(ushort2*)((unsigned short*)Y + o) = w;
  } else if (f32) {
    float2 w; w.x = r0; w.y = r1;
    *(float2*)((float*)Y + o) = w;
  } else {
    ushort2 w; w.x = f2bf(r0); w.y = f2bf(r1);
    *(ushort2*)((unsigned short*)Y + o) = w;
  }
}

extern "C" void kernel_launch(void* const* d_in, const int* in_sizes, int n_in,
                              void* d_out, int out_size, void* d_ws, size_t ws_size,
                              hipStream_t stream)
{
  const void* x   = d_in[0];
  const int*  ei  = (const int*)d_in[1];
  const void* W1  = d_in[2];
  const void* as1 = d_in[3];
  const void* ad1 = d_in[4];
  const void* b1  = d_in[5];
  const void* W2  = d_in[6];
  const void* as2 = d_in[7];
  const void* ad2 = d_in[8];
  const void* b2  = d_in[9];

  char* ws = (char*)d_ws;
  unsigned short* H  = (unsigned short*)(ws);            // 12,800,000 B (fp16)
  float*  AS         = (float*)(ws + 12800000);          //    800,000 B
  float*  AD         = (float*)(ws + 13600000);          //    800,000 B
  unsigned short* X2 = (unsigned short*)(ws + 14400000); // 12,800,000 B
  int*    deg        = (int*)(ws + 27200000);            //    200,000 B
  int*    row_ptr    = (int*)(ws + 27400000);            //    200,000 B
  int*    csr_src    = (int*)(ws + 27600000);            //  2,760,000 B
  int*    MT         = (int*)(ws + 30360000);            //    269,696 B
  int*    T          = (int*)(ws + 30630000);            //        784 B
  int*    BB         = (int*)(ws + 30631000);            //        788 B
  int*    flags      = (int*)(ws + 30632000);            //         64 B
  int2*   ebuf       = (int2*)(ws + 30640000);           //  5,520,000 B
  unsigned short* Wt1 = (unsigned short*)(ws + 36160000); //    32,768 B
  unsigned short* Wt2 = (unsigned short*)(ws + 36200000); //    32,768 B
  unsigned short* Ba1 = (unsigned short*)(ws + 36240000); //     4,096 B
  unsigned short* Ba2 = (unsigned short*)(ws + 36248000); //     4,096 B

  const int agg_blocks = (N_NODES + 3) / 4;              // 1 wave per node

  k_detect<<<1, 256, 0, stream>>>((const unsigned short*)x,
                                  (const unsigned int*)ei, flags);
  k_prep<<<264, 256, 0, stream>>>(W1, W2, as1, ad1, as2, ad2,
                                  Wt1, Wt2, Ba1, Ba2, flags);

  // ---- layer-1 GEMM overlapped with bucket histogram (pass A) ----
  k_gemm_hist<<<GEMMB + NEB, 256, 0, stream>>>(
      x, Wt1, Ba1, H, AS, AD, N_NODES, ei, MT, flags);

  // ---- CSR build, atomic-free ----
  k_rowscan<<<NBUCK, 512, 0, stream>>>(MT, T);
  k_bscan  <<<1, 256, 0, stream>>>(T, BB);
  k_bucket <<<NEB, 256, 0, stream>>>(ei, MT, BB, ebuf, flags);
  k_fine   <<<NBUCK, 256, 0, stream>>>(ebuf, BB, row_ptr, deg, csr_src);

  // ---- layer 1 aggregate ----
  k_agg<<<agg_blocks, 256, 0, stream>>>(row_ptr, deg, csr_src,
                                        (const __half*)H, AS, AD,
                                        b1, X2, flags, 1);

  // ---- layer 2 ----
  k_gemm<<<GEMMB, 256, 0, stream>>>(X2, Wt2, Ba2, H, AS, AD, N_NODES);
  k_agg<<<agg_blocks, 256, 0, stream>>>(row_ptr, deg, csr_src,
                                        (const __half*)H, AS, AD,
                                        b2, d_out, flags, 2);
}